// Round 4
// baseline (108.490 us; speedup 1.0000x reference)
//
#include <hip/hip_runtime.h>
#include <stdint.h>

// Problem constants: B=32, N=1024, C=64, G=64
// ws layout (fp16): q_ws[32768][64] | k_ws[32768][64] | vt_ws[32][64][1024]  => 12 MB

typedef __attribute__((ext_vector_type(4))) float    floatx4;
typedef __attribute__((ext_vector_type(8))) _Float16 halfx8;

static __device__ __forceinline__ unsigned short f2h(float f) {
    union { _Float16 h; unsigned short u; } v; v.h = (_Float16)f;
    return v.u;
}
static __device__ __forceinline__ float h2f(unsigned short u) {
    union { unsigned short u; _Float16 h; } v; v.u = u;
    return (float)v.h;
}

// ---------------------------------------------------------------------------
// Kernel 1: QKV projection, split-precision fp16 MFMA (x=x_hi+x_lo, W=W_hi+W_lo;
// q = x_hi*W_hi + x_hi*W_lo + x_lo*W_hi  -> ~fp32-accurate before fp16 store).
// grid=512 x 256. q,k -> row-major fp16; v -> transposed [g][n] fp16.
// ---------------------------------------------------------------------------
__global__ __launch_bounds__(256) void qkv_proj_kernel(
    const float* __restrict__ x,
    const float* __restrict__ Wq, const float* __restrict__ bq,
    const float* __restrict__ Wk, const float* __restrict__ bk,
    const float* __restrict__ Wv, const float* __restrict__ bv,
    unsigned short* __restrict__ q_ws, unsigned short* __restrict__ k_ws,
    unsigned short* __restrict__ vt_ws)
{
    // layout: [0..4096)=xs_hi, [4096..8192)=xs_lo, then 6x4096 = wT[wi][hi/lo]
    __shared__ __align__(16) unsigned short smem[8 * 64 * 64];   // 64 KB
    float* vtmp = (float*)&smem[2 * 64 * 64];                    // aliases wT region (needs 16.7 KB of 48)

    const int XS_HI = 0, XS_LO = 64 * 64;
    #define WT_OFF(i) (2 * 64 * 64 + (i) * 64 * 64)

    const int tid  = threadIdx.x;
    const int blk  = blockIdx.x;          // 0..511
    const int row0 = blk * 64;            // global row base (b*1024 + n0)
    const int b    = blk >> 4;
    const int n0   = (blk & 15) * 64;
    const int lane = tid & 63;
    const int w    = tid >> 6;            // wave 0..3
    const int l15  = lane & 15;
    const int quad = lane >> 4;

    // --- stage x -> xs_hi/xs_lo (fp16 split, XOR-8 chunk swizzle) ---
#pragma unroll
    for (int i = 0; i < 2; ++i) {
        int id = i * 256 + tid;           // 0..511 chunks of 8 elems
        int r = id >> 3, c8 = id & 7;
        const float4* gp = (const float4*)(x + (row0 + r) * 64 + c8 * 8);
        float4 f0 = gp[0], f1 = gp[1];
        float fv[8] = { f0.x, f0.y, f0.z, f0.w, f1.x, f1.y, f1.z, f1.w };
        __align__(16) unsigned short thi[8], tlo[8];
#pragma unroll
        for (int j = 0; j < 8; ++j) {
            unsigned short hi = f2h(fv[j]);
            thi[j] = hi;
            tlo[j] = f2h(fv[j] - h2f(hi));
        }
        int idx = r * 64 + ((c8 ^ (r & 7)) * 8);
        *(uint4*)&smem[XS_HI + idx] = *(uint4*)thi;
        *(uint4*)&smem[XS_LO + idx] = *(uint4*)tlo;
    }
    // --- stage W^T hi/lo (fp16 split, swizzled) ---
    {
        const float* Ws[3] = { Wq, Wk, Wv };
        int g = tid & 63, ci = tid >> 6;
#pragma unroll
        for (int wi = 0; wi < 3; ++wi) {
#pragma unroll
            for (int j = 0; j < 16; ++j) {
                int c = ci * 16 + j;
                float f = Ws[wi][c * 64 + g];
                unsigned short hi = f2h(f);
                unsigned short lo = f2h(f - h2f(hi));
                int c8 = c >> 3;
                int idx = g * 64 + ((c8 ^ (g & 7)) * 8) + (c & 7);
                smem[WT_OFF(wi * 2 + 0) + idx] = hi;
                smem[WT_OFF(wi * 2 + 1) + idx] = lo;
            }
        }
    }
    __syncthreads();

    // A-fragments: rows w*16 + l15, k-chunk kc -> chunk idx kc*4+quad
    const int arow = w * 16 + l15;
    const int aidx0 = arow * 64 + (((0 + quad) ^ (arow & 7)) * 8);
    const int aidx1 = arow * 64 + (((4 + quad) ^ (arow & 7)) * 8);
    halfx8 a_hi0 = *(const halfx8*)&smem[XS_HI + aidx0];
    halfx8 a_hi1 = *(const halfx8*)&smem[XS_HI + aidx1];
    halfx8 a_lo0 = *(const halfx8*)&smem[XS_LO + aidx0];
    halfx8 a_lo1 = *(const halfx8*)&smem[XS_LO + aidx1];

    const float* biases[3] = { bq, bk, bv };
    floatx4 vacc[4];
#pragma unroll
    for (int wi = 0; wi < 3; ++wi) {
#pragma unroll
        for (int gs = 0; gs < 4; ++gs) {
            int g0 = gs * 16;
            float bias = biases[wi][g0 + l15];
            floatx4 acc = { bias, bias, bias, bias };   // D init = bias[col]
            int brow = g0 + l15;
            int bidx0 = brow * 64 + (((0 + quad) ^ (brow & 7)) * 8);
            int bidx1 = brow * 64 + (((4 + quad) ^ (brow & 7)) * 8);
            halfx8 b_hi0 = *(const halfx8*)&smem[WT_OFF(wi * 2 + 0) + bidx0];
            halfx8 b_hi1 = *(const halfx8*)&smem[WT_OFF(wi * 2 + 0) + bidx1];
            halfx8 b_lo0 = *(const halfx8*)&smem[WT_OFF(wi * 2 + 1) + bidx0];
            halfx8 b_lo1 = *(const halfx8*)&smem[WT_OFF(wi * 2 + 1) + bidx1];
            acc = __builtin_amdgcn_mfma_f32_16x16x32_f16(a_hi0, b_hi0, acc, 0, 0, 0);
            acc = __builtin_amdgcn_mfma_f32_16x16x32_f16(a_hi1, b_hi1, acc, 0, 0, 0);
            acc = __builtin_amdgcn_mfma_f32_16x16x32_f16(a_hi0, b_lo0, acc, 0, 0, 0);
            acc = __builtin_amdgcn_mfma_f32_16x16x32_f16(a_hi1, b_lo1, acc, 0, 0, 0);
            acc = __builtin_amdgcn_mfma_f32_16x16x32_f16(a_lo0, b_hi0, acc, 0, 0, 0);
            acc = __builtin_amdgcn_mfma_f32_16x16x32_f16(a_lo1, b_hi1, acc, 0, 0, 0);
            if (wi < 2) {
                unsigned short* dst = (wi == 0) ? q_ws : k_ws;
#pragma unroll
                for (int r = 0; r < 4; ++r) {
                    int row = row0 + w * 16 + quad * 4 + r;   // C/D: row=quad*4+reg
                    dst[row * 64 + g0 + l15] = f2h(acc[r]);   // col = l15 (+g0)
                }
            } else {
                vacc[gs] = acc;
            }
        }
    }

    // all waves done reading wT -> safe to alias vtmp over it
    __syncthreads();
#pragma unroll
    for (int gs = 0; gs < 4; ++gs) {
#pragma unroll
        for (int r = 0; r < 4; ++r) {
            int nl = w * 16 + quad * 4 + r;
            vtmp[(gs * 16 + l15) * 65 + nl] = vacc[gs][r];
        }
    }
    __syncthreads();

    // --- vtmp [g][n_local] -> vt_ws global fp16, coalesced ---
    {
        int g = tid >> 2, c4 = tid & 3;
        __align__(16) unsigned short tmp[16];
#pragma unroll
        for (int j = 0; j < 16; ++j) tmp[j] = f2h(vtmp[g * 65 + c4 * 16 + j]);
        unsigned short* dst = vt_ws + (b * 64 + g) * 1024 + n0 + c4 * 16;
        *(uint4*)(dst)     = ((uint4*)tmp)[0];
        *(uint4*)(dst + 8) = ((uint4*)tmp)[1];
    }
    #undef WT_OFF
}

// ---------------------------------------------------------------------------
// Kernel 2: flash attention.  grid=512 blocks x 256 threads.
// Block = 64 q-rows (4 waves x 16). Loop over 64-key tiles of K and V^T.
// ---------------------------------------------------------------------------
__global__ __launch_bounds__(256) void attn_kernel(
    const unsigned short* __restrict__ q_ws, const unsigned short* __restrict__ k_ws,
    const unsigned short* __restrict__ vt_ws, const int* __restrict__ valid_len,
    float* __restrict__ out)
{
    __shared__ __align__(16) unsigned short qs[64 * 64];
    __shared__ __align__(16) unsigned short ks[64 * 64];
    __shared__ __align__(16) unsigned short vs[64 * 64];     // V^T tile [g][key]
    __shared__ __align__(16) float ps[4][16 * 68];           // per-wave P, padded

    const int tid  = threadIdx.x;
    const int blk  = blockIdx.x;
    const int b    = blk >> 4;
    const int row0 = blk * 64;
    const int lane = tid & 63;
    const int w    = tid >> 6;
    const int l15  = lane & 15;
    const int quad = lane >> 4;

    // stage q tile once (already fp16 in ws)
#pragma unroll
    for (int i = 0; i < 2; ++i) {
        int id = i * 256 + tid;
        int r = id >> 3, c8 = id & 7;
        uint4 d = *(const uint4*)(q_ws + (row0 + r) * 64 + c8 * 8);
        *(uint4*)&qs[r * 64 + ((c8 ^ (r & 7)) * 8)] = d;
    }

    const int vl = valid_len[b];
    const int ntiles = (vl == 0) ? 16 : ((vl + 63) >> 6);   // skipped tiles are exact-0

    float m_r[4] = { -INFINITY, -INFINITY, -INFINITY, -INFINITY };
    float l_r[4] = { 0.f, 0.f, 0.f, 0.f };
    floatx4 o[4] = { {0,0,0,0}, {0,0,0,0}, {0,0,0,0}, {0,0,0,0} };

    const int arow = w * 16 + l15;

    for (int t = 0; t < ntiles; ++t) {
        __syncthreads();   // previous tile fully consumed (also covers qs staging)
#pragma unroll
        for (int i = 0; i < 2; ++i) {
            int id = i * 256 + tid;
            int r = id >> 3, c8 = id & 7;
            uint4 dk = *(const uint4*)(k_ws + (b * 1024 + t * 64 + r) * 64 + c8 * 8);
            *(uint4*)&ks[r * 64 + ((c8 ^ (r & 7)) * 8)] = dk;
            uint4 dv = *(const uint4*)(vt_ws + (b * 64 + r) * 1024 + t * 64 + c8 * 8);
            *(uint4*)&vs[r * 64 + ((c8 ^ (r & 7)) * 8)] = dv;
        }
        __syncthreads();

        halfx8 aq0 = *(const halfx8*)&qs[arow * 64 + (((0 + quad) ^ (arow & 7)) * 8)];
        halfx8 aq1 = *(const halfx8*)&qs[arow * 64 + (((4 + quad) ^ (arow & 7)) * 8)];

        // ---- S = Q K^T  (D: row=q=quad*4+reg, col=key=sub*16+l15) ----
        floatx4 s[4];
#pragma unroll
        for (int sub = 0; sub < 4; ++sub) {
            int krow = sub * 16 + l15;
            halfx8 bk0 = *(const halfx8*)&ks[krow * 64 + (((0 + quad) ^ (krow & 7)) * 8)];
            halfx8 bk1 = *(const halfx8*)&ks[krow * 64 + (((4 + quad) ^ (krow & 7)) * 8)];
            floatx4 acc = { 0, 0, 0, 0 };
            acc = __builtin_amdgcn_mfma_f32_16x16x32_f16(aq0, bk0, acc, 0, 0, 0);
            acc = __builtin_amdgcn_mfma_f32_16x16x32_f16(aq1, bk1, acc, 0, 0, 0);
            int key = t * 64 + sub * 16 + l15;
            if (key >= vl) { acc[0] = -1e6f; acc[1] = -1e6f; acc[2] = -1e6f; acc[3] = -1e6f; }
            s[sub] = acc;
        }

        // ---- online softmax per q-row (reduce over 16-lane col groups) ----
        float p[4][4];       // [sub][reg]
        float alpha[4];
#pragma unroll
        for (int r = 0; r < 4; ++r) {
            float mx = fmaxf(fmaxf(s[0][r], s[1][r]), fmaxf(s[2][r], s[3][r]));
#pragma unroll
            for (int off = 1; off < 16; off <<= 1)
                mx = fmaxf(mx, __shfl_xor(mx, off, 64));
            float mnew = fmaxf(m_r[r], mx);
            alpha[r] = __expf(m_r[r] - mnew);     // exp(-inf)=0 on first tile
            float sum = 0.f;
#pragma unroll
            for (int sub = 0; sub < 4; ++sub) {
                float pv = __expf(s[sub][r] - mnew);
                p[sub][r] = pv;
                sum += pv;
            }
#pragma unroll
            for (int off = 1; off < 16; off <<= 1)
                sum += __shfl_xor(sum, off, 64);
            l_r[r] = l_r[r] * alpha[r] + sum;
            m_r[r] = mnew;
        }
#pragma unroll
        for (int gs = 0; gs < 4; ++gs) {
            o[gs][0] *= alpha[0]; o[gs][1] *= alpha[1];
            o[gs][2] *= alpha[2]; o[gs][3] *= alpha[3];
        }

        // ---- transpose P through wave-private LDS (D-layout -> A-layout) ----
        float* psw = ps[w];
#pragma unroll
        for (int sub = 0; sub < 4; ++sub)
#pragma unroll
            for (int r = 0; r < 4; ++r)
                psw[(quad * 4 + r) * 68 + sub * 16 + l15] = p[sub][r];

        halfx8 ap[2];
#pragma unroll
        for (int kc = 0; kc < 2; ++kc) {
            const float* src = &psw[l15 * 68 + kc * 32 + quad * 8];
            float4 f0 = *(const float4*)src;
            float4 f1 = *(const float4*)(src + 4);
            __align__(16) unsigned short tmp[8] = {
                f2h(f0.x), f2h(f0.y), f2h(f0.z), f2h(f0.w),
                f2h(f1.x), f2h(f1.y), f2h(f1.z), f2h(f1.w) };
            ap[kc] = *(halfx8*)tmp;
        }

        // ---- O += P V  (B-operand from V^T tile, k-contiguous) ----
#pragma unroll
        for (int gs = 0; gs < 4; ++gs) {
            int grow = gs * 16 + l15;
            halfx8 bv0 = *(const halfx8*)&vs[grow * 64 + (((0 + quad) ^ (grow & 7)) * 8)];
            halfx8 bv1 = *(const halfx8*)&vs[grow * 64 + (((4 + quad) ^ (grow & 7)) * 8)];
            o[gs] = __builtin_amdgcn_mfma_f32_16x16x32_f16(ap[0], bv0, o[gs], 0, 0, 0);
            o[gs] = __builtin_amdgcn_mfma_f32_16x16x32_f16(ap[1], bv1, o[gs], 0, 0, 0);
        }
    }

    // ---- epilogue: O / l, fp32 store ----
#pragma unroll
    for (int gs = 0; gs < 4; ++gs) {
#pragma unroll
        for (int r = 0; r < 4; ++r) {
            int row = row0 + w * 16 + quad * 4 + r;
            out[row * 64 + gs * 16 + l15] = o[gs][r] / l_r[r];
        }
    }
}

// ---------------------------------------------------------------------------
extern "C" void kernel_launch(void* const* d_in, const int* in_sizes, int n_in,
                              void* d_out, int out_size, void* d_ws, size_t ws_size,
                              hipStream_t stream) {
    const float* x    = (const float*)d_in[0];
    const int*   vlen = (const int*)  d_in[1];
    const float* Wq   = (const float*)d_in[2];
    const float* bq   = (const float*)d_in[3];
    const float* Wk   = (const float*)d_in[4];
    const float* bk   = (const float*)d_in[5];
    const float* Wv   = (const float*)d_in[6];
    const float* bv   = (const float*)d_in[7];
    float* out = (float*)d_out;

    unsigned short* q_ws  = (unsigned short*)d_ws;
    unsigned short* k_ws  = q_ws + 32768 * 64;
    unsigned short* vt_ws = k_ws + 32768 * 64;

    qkv_proj_kernel<<<512, 256, 0, stream>>>(x, Wq, bq, Wk, bk, Wv, bv, q_ws, k_ws, vt_ws);
    attn_kernel<<<512, 256, 0, stream>>>(q_ws, k_ws, vt_ws, vlen, out);
}

// Round 5
// 106.812 us; speedup vs baseline: 1.0157x; 1.0157x over previous
//
#include <hip/hip_runtime.h>
#include <stdint.h>

// Problem constants: B=32, N=1024, C=64, G=64
// ws layout (fp16): q_ws[32768][64] | k_ws[32768][64] | vt_ws[32][64][1024]  => 12 MB

typedef __attribute__((ext_vector_type(4))) float    floatx4;
typedef __attribute__((ext_vector_type(8))) _Float16 halfx8;

static __device__ __forceinline__ unsigned short f2h(float f) {
    union { _Float16 h; unsigned short u; } v; v.h = (_Float16)f;
    return v.u;
}
static __device__ __forceinline__ float h2f(unsigned short u) {
    union { unsigned short u; _Float16 h; } v; v.u = u;
    return (float)v.h;
}

// ---------------------------------------------------------------------------
// Kernel 1: QKV projection, split-precision fp16 MFMA (x=x_hi+x_lo, W=W_hi+W_lo).
// q,k: MFMA C-layout -> fp16 LDS (xor-swizzled) -> coalesced uint4 global stores.
// v -> fp32 LDS transpose -> vt_ws [g][n] fp16.
// ---------------------------------------------------------------------------
__global__ __launch_bounds__(256) void qkv_proj_kernel(
    const float* __restrict__ x,
    const float* __restrict__ Wq, const float* __restrict__ bq,
    const float* __restrict__ Wk, const float* __restrict__ bk,
    const float* __restrict__ Wv, const float* __restrict__ bv,
    unsigned short* __restrict__ q_ws, unsigned short* __restrict__ k_ws,
    unsigned short* __restrict__ vt_ws)
{
    // [0,4096)=xs_hi / later q_lds ; [4096,8192)=xs_lo / later k_lds ; 6x4096 wT
    __shared__ __align__(16) unsigned short smem[8 * 4096];      // 64 KB
    float* vtmp = (float*)&smem[2 * 4096];                       // aliases wT (post-MFMA)

    const int XS_HI = 0, XS_LO = 4096;
    #define WT_OFF(i) (2 * 4096 + (i) * 4096)

    const int tid  = threadIdx.x;
    const int blk  = blockIdx.x;          // 0..511
    const int row0 = blk * 64;
    const int b    = blk >> 4;
    const int n0   = (blk & 15) * 64;
    const int lane = tid & 63;
    const int w    = tid >> 6;
    const int l15  = lane & 15;
    const int quad = lane >> 4;

    // --- stage x -> xs_hi/xs_lo (fp16 split, XOR-8 chunk swizzle) ---
#pragma unroll
    for (int i = 0; i < 2; ++i) {
        int id = i * 256 + tid;
        int r = id >> 3, c8 = id & 7;
        const float4* gp = (const float4*)(x + (row0 + r) * 64 + c8 * 8);
        float4 f0 = gp[0], f1 = gp[1];
        float fv[8] = { f0.x, f0.y, f0.z, f0.w, f1.x, f1.y, f1.z, f1.w };
        __align__(16) unsigned short thi[8], tlo[8];
#pragma unroll
        for (int j = 0; j < 8; ++j) {
            unsigned short hi = f2h(fv[j]);
            thi[j] = hi;
            tlo[j] = f2h(fv[j] - h2f(hi));
        }
        int idx = r * 64 + ((c8 ^ (r & 7)) * 8);
        *(uint4*)&smem[XS_HI + idx] = *(uint4*)thi;
        *(uint4*)&smem[XS_LO + idx] = *(uint4*)tlo;
    }
    // --- stage W^T hi/lo (fp16 split, swizzled; g=lane -> coalesced) ---
    {
        const float* Ws[3] = { Wq, Wk, Wv };
        int g = tid & 63, ci = tid >> 6;
#pragma unroll
        for (int wi = 0; wi < 3; ++wi) {
#pragma unroll
            for (int j = 0; j < 16; ++j) {
                int c = ci * 16 + j;
                float f = Ws[wi][c * 64 + g];
                unsigned short hi = f2h(f);
                unsigned short lo = f2h(f - h2f(hi));
                int c8 = c >> 3;
                int idx = g * 64 + ((c8 ^ (g & 7)) * 8) + (c & 7);
                smem[WT_OFF(wi * 2 + 0) + idx] = hi;
                smem[WT_OFF(wi * 2 + 1) + idx] = lo;
            }
        }
    }
    __syncthreads();

    // A-fragments
    const int arow = w * 16 + l15;
    const int aidx0 = arow * 64 + (((0 + quad) ^ (arow & 7)) * 8);
    const int aidx1 = arow * 64 + (((4 + quad) ^ (arow & 7)) * 8);
    halfx8 a_hi0 = *(const halfx8*)&smem[XS_HI + aidx0];
    halfx8 a_hi1 = *(const halfx8*)&smem[XS_HI + aidx1];
    halfx8 a_lo0 = *(const halfx8*)&smem[XS_LO + aidx0];
    halfx8 a_lo1 = *(const halfx8*)&smem[XS_LO + aidx1];

    __syncthreads();   // all frags loaded -> xs region reusable as q_lds/k_lds

    unsigned short* q_lds = &smem[0];
    unsigned short* k_lds = &smem[4096];

    const float* biases[3] = { bq, bk, bv };
    floatx4 vacc[4];
#pragma unroll
    for (int wi = 0; wi < 3; ++wi) {
#pragma unroll
        for (int gs = 0; gs < 4; ++gs) {
            int g0 = gs * 16;
            float bias = biases[wi][g0 + l15];
            floatx4 acc = { bias, bias, bias, bias };
            int brow = g0 + l15;
            int bidx0 = brow * 64 + (((0 + quad) ^ (brow & 7)) * 8);
            int bidx1 = brow * 64 + (((4 + quad) ^ (brow & 7)) * 8);
            halfx8 b_hi0 = *(const halfx8*)&smem[WT_OFF(wi * 2 + 0) + bidx0];
            halfx8 b_hi1 = *(const halfx8*)&smem[WT_OFF(wi * 2 + 0) + bidx1];
            halfx8 b_lo0 = *(const halfx8*)&smem[WT_OFF(wi * 2 + 1) + bidx0];
            halfx8 b_lo1 = *(const halfx8*)&smem[WT_OFF(wi * 2 + 1) + bidx1];
            acc = __builtin_amdgcn_mfma_f32_16x16x32_f16(a_hi0, b_hi0, acc, 0, 0, 0);
            acc = __builtin_amdgcn_mfma_f32_16x16x32_f16(a_hi1, b_hi1, acc, 0, 0, 0);
            acc = __builtin_amdgcn_mfma_f32_16x16x32_f16(a_hi0, b_lo0, acc, 0, 0, 0);
            acc = __builtin_amdgcn_mfma_f32_16x16x32_f16(a_hi1, b_lo1, acc, 0, 0, 0);
            acc = __builtin_amdgcn_mfma_f32_16x16x32_f16(a_lo0, b_hi0, acc, 0, 0, 0);
            acc = __builtin_amdgcn_mfma_f32_16x16x32_f16(a_lo1, b_hi1, acc, 0, 0, 0);
            if (wi < 2) {
                unsigned short* dst = (wi == 0) ? q_lds : k_lds;
                int c8 = gs * 2 + (l15 >> 3);
#pragma unroll
                for (int r = 0; r < 4; ++r) {
                    int row = w * 16 + quad * 4 + r;   // wave-private rows
                    dst[row * 64 + ((c8 ^ (row & 7)) * 8) + (l15 & 7)] = f2h(acc[r]);
                }
            } else {
                vacc[gs] = acc;
            }
        }
    }

    __syncthreads();   // MFMAs done (wT free for vtmp), q/k LDS complete

    // --- coalesced q/k stores (uint4 = 8 fp16) ---
#pragma unroll
    for (int i = 0; i < 2; ++i) {
        int id = i * 256 + tid;
        int r = id >> 3, c8 = id & 7;
        int sidx = r * 64 + ((c8 ^ (r & 7)) * 8);
        *(uint4*)(q_ws + (row0 + r) * 64 + c8 * 8) = *(const uint4*)&q_lds[sidx];
        *(uint4*)(k_ws + (row0 + r) * 64 + c8 * 8) = *(const uint4*)&k_lds[sidx];
    }

    // --- v transpose through fp32 LDS ---
#pragma unroll
    for (int gs = 0; gs < 4; ++gs) {
#pragma unroll
        for (int r = 0; r < 4; ++r) {
            int nl = w * 16 + quad * 4 + r;
            vtmp[(gs * 16 + l15) * 65 + nl] = vacc[gs][r];
        }
    }
    __syncthreads();
    {
        int g = tid >> 2, c4 = tid & 3;
        __align__(16) unsigned short tmp[16];
#pragma unroll
        for (int j = 0; j < 16; ++j) tmp[j] = f2h(vtmp[g * 65 + c4 * 16 + j]);
        unsigned short* dst = vt_ws + (b * 64 + g) * 1024 + n0 + c4 * 16;
        *(uint4*)(dst)     = ((uint4*)tmp)[0];
        *(uint4*)(dst + 8) = ((uint4*)tmp)[1];
    }
    #undef WT_OFF
}

// ---------------------------------------------------------------------------
// Kernel 2: two-pass flash attention (bounded scores => exact-max two-pass).
// Pass 1: row max only (no shuffles in loop). Pass 2: p=exp(s-m), deferred sum,
// PV. Double-buffered K/V staging, one barrier per tile, register prefetch.
// grid=512 x 256; block = 64 q-rows (4 waves x 16 rows).
// ---------------------------------------------------------------------------
__global__ __launch_bounds__(256) void attn_kernel(
    const unsigned short* __restrict__ q_ws, const unsigned short* __restrict__ k_ws,
    const unsigned short* __restrict__ vt_ws, const int* __restrict__ valid_len,
    float* __restrict__ out)
{
    __shared__ __align__(16) unsigned short qs[4096];        // 8 KB
    __shared__ __align__(16) unsigned short kbuf[2][4096];   // 16 KB
    __shared__ __align__(16) unsigned short vbuf[2][4096];   // 16 KB
    __shared__ __align__(16) unsigned short ps[4 * 1024];    // 8 KB fp16 P, per-wave

    const int tid  = threadIdx.x;
    const int blk  = blockIdx.x;
    const int b    = blk >> 4;
    const int row0 = blk * 64;
    const int lane = tid & 63;
    const int w    = tid >> 6;
    const int l15  = lane & 15;
    const int quad = lane >> 4;

    // chunk coordinates for staging (2 chunks per thread)
    const int r_a  = tid >> 3,          c8_a = tid & 7;
    const int r_b  = (256 + tid) >> 3,  c8_b = tid & 7;
    const int lidx_a = r_a * 64 + ((c8_a ^ (r_a & 7)) * 8);
    const int lidx_b = r_b * 64 + ((c8_b ^ (r_b & 7)) * 8);

    // --- stage q tile (fp16, swizzled) ---
    *(uint4*)&qs[lidx_a] = *(const uint4*)(q_ws + (row0 + r_a) * 64 + c8_a * 8);
    *(uint4*)&qs[lidx_b] = *(const uint4*)(q_ws + (row0 + r_b) * 64 + c8_b * 8);

    const int vl    = valid_len[b];
    const float mv  = (vl > 0) ? -1000000.0f : 0.0f;   // vl==0 -> uniform softmax
    const int nt    = (vl == 0) ? 16 : ((vl + 63) >> 6);
    const int fullt = vl >> 6;                          // tiles [0,fullt) need no mask

    const unsigned short* kbase = k_ws + (size_t)b * 1024 * 64;
    const unsigned short* vbase = vt_ws + (size_t)b * 64 * 1024;

    // ---- pass 1 prologue: prefetch K(0), write kbuf[0] ----
    uint4 kr0 = *(const uint4*)(kbase + r_a * 64 + c8_a * 8);
    uint4 kr1 = *(const uint4*)(kbase + r_b * 64 + c8_b * 8);
    *(uint4*)&kbuf[0][lidx_a] = kr0;
    *(uint4*)&kbuf[0][lidx_b] = kr1;

    __syncthreads();   // qs + kbuf[0] visible

    const int arow = w * 16 + l15;
    halfx8 aq0 = *(const halfx8*)&qs[arow * 64 + (((0 + quad) ^ (arow & 7)) * 8)];
    halfx8 aq1 = *(const halfx8*)&qs[arow * 64 + (((4 + quad) ^ (arow & 7)) * 8)];

    // ---- pass 1: per-lane running max ----
    float m_lane[4] = { -1000000.0f, -1000000.0f, -1000000.0f, -1000000.0f };
    for (int t = 0; t < nt; ++t) {
        bool pre = (t + 1) < nt;
        if (pre) {
            const unsigned short* kp = kbase + (t + 1) * 64 * 64;
            kr0 = *(const uint4*)(kp + r_a * 64 + c8_a * 8);
            kr1 = *(const uint4*)(kp + r_b * 64 + c8_b * 8);
        }
        __syncthreads();                       // buf[t&1] complete; prior reads drained
        if (pre) {
            *(uint4*)&kbuf[(t + 1) & 1][lidx_a] = kr0;
            *(uint4*)&kbuf[(t + 1) & 1][lidx_b] = kr1;
        }
        const unsigned short* ksb = kbuf[t & 1];

        floatx4 s[4];
#pragma unroll
        for (int sub = 0; sub < 4; ++sub) {
            int krow = sub * 16 + l15;
            halfx8 bk0 = *(const halfx8*)&ksb[krow * 64 + (((0 + quad) ^ (krow & 7)) * 8)];
            halfx8 bk1 = *(const halfx8*)&ksb[krow * 64 + (((4 + quad) ^ (krow & 7)) * 8)];
            floatx4 acc = { 0, 0, 0, 0 };
            acc = __builtin_amdgcn_mfma_f32_16x16x32_f16(aq0, bk0, acc, 0, 0, 0);
            acc = __builtin_amdgcn_mfma_f32_16x16x32_f16(aq1, bk1, acc, 0, 0, 0);
            s[sub] = acc;
        }
        if (t >= fullt) {
#pragma unroll
            for (int sub = 0; sub < 4; ++sub) {
                int key = t * 64 + sub * 16 + l15;
                if (key >= vl) { s[sub][0] = mv; s[sub][1] = mv; s[sub][2] = mv; s[sub][3] = mv; }
            }
        }
#pragma unroll
        for (int r = 0; r < 4; ++r)
            m_lane[r] = fmaxf(m_lane[r],
                        fmaxf(fmaxf(s[0][r], s[1][r]), fmaxf(s[2][r], s[3][r])));
    }

    // ---- butterfly 16-lane max (once) ----
    float m[4];
#pragma unroll
    for (int r = 0; r < 4; ++r) {
        float mm = m_lane[r];
#pragma unroll
        for (int off = 1; off < 16; off <<= 1)
            mm = fmaxf(mm, __shfl_xor(mm, off, 64));
        m[r] = mm;
    }

    // ---- pass 2 prologue ----
    kr0 = *(const uint4*)(kbase + r_a * 64 + c8_a * 8);
    kr1 = *(const uint4*)(kbase + r_b * 64 + c8_b * 8);
    uint4 vr0 = *(const uint4*)(vbase + r_a * 1024 + c8_a * 8);
    uint4 vr1 = *(const uint4*)(vbase + r_b * 1024 + c8_b * 8);
    __syncthreads();   // pass-1 LDS reads done before overwriting bufs
    *(uint4*)&kbuf[0][lidx_a] = kr0;
    *(uint4*)&kbuf[0][lidx_b] = kr1;
    *(uint4*)&vbuf[0][lidx_a] = vr0;
    *(uint4*)&vbuf[0][lidx_b] = vr1;

    float l_lane[4] = { 0.f, 0.f, 0.f, 0.f };
    floatx4 o[4] = { {0,0,0,0}, {0,0,0,0}, {0,0,0,0}, {0,0,0,0} };

    for (int t = 0; t < nt; ++t) {
        bool pre = (t + 1) < nt;
        if (pre) {
            const unsigned short* kp = kbase + (t + 1) * 64 * 64;
            const unsigned short* vp = vbase + (t + 1) * 64;
            kr0 = *(const uint4*)(kp + r_a * 64 + c8_a * 8);
            kr1 = *(const uint4*)(kp + r_b * 64 + c8_b * 8);
            vr0 = *(const uint4*)(vp + r_a * 1024 + c8_a * 8);
            vr1 = *(const uint4*)(vp + r_b * 1024 + c8_b * 8);
        }
        __syncthreads();
        if (pre) {
            *(uint4*)&kbuf[(t + 1) & 1][lidx_a] = kr0;
            *(uint4*)&kbuf[(t + 1) & 1][lidx_b] = kr1;
            *(uint4*)&vbuf[(t + 1) & 1][lidx_a] = vr0;
            *(uint4*)&vbuf[(t + 1) & 1][lidx_b] = vr1;
        }
        const unsigned short* ksb = kbuf[t & 1];
        const unsigned short* vsb = vbuf[t & 1];

        floatx4 s[4];
#pragma unroll
        for (int sub = 0; sub < 4; ++sub) {
            int krow = sub * 16 + l15;
            halfx8 bk0 = *(const halfx8*)&ksb[krow * 64 + (((0 + quad) ^ (krow & 7)) * 8)];
            halfx8 bk1 = *(const halfx8*)&ksb[krow * 64 + (((4 + quad) ^ (krow & 7)) * 8)];
            floatx4 acc = { 0, 0, 0, 0 };
            acc = __builtin_amdgcn_mfma_f32_16x16x32_f16(aq0, bk0, acc, 0, 0, 0);
            acc = __builtin_amdgcn_mfma_f32_16x16x32_f16(aq1, bk1, acc, 0, 0, 0);
            s[sub] = acc;
        }
        if (t >= fullt) {
#pragma unroll
            for (int sub = 0; sub < 4; ++sub) {
                int key = t * 64 + sub * 16 + l15;
                if (key >= vl) { s[sub][0] = mv; s[sub][1] = mv; s[sub][2] = mv; s[sub][3] = mv; }
            }
        }

        // p = exp(s - m); deferred row-sum; write P (fp16, A-layout via LDS)
        unsigned short* psw = &ps[w * 1024];
#pragma unroll
        for (int sub = 0; sub < 4; ++sub) {
            int c8 = sub * 2 + (l15 >> 3);
#pragma unroll
            for (int r = 0; r < 4; ++r) {
                float p = __expf(s[sub][r] - m[r]);
                l_lane[r] += p;
                int row = quad * 4 + r;
                psw[row * 64 + ((c8 ^ (row & 7)) * 8) + (l15 & 7)] = f2h(p);
            }
        }
        halfx8 ap0 = *(const halfx8*)&psw[l15 * 64 + (((0 + quad) ^ (l15 & 7)) * 8)];
        halfx8 ap1 = *(const halfx8*)&psw[l15 * 64 + (((4 + quad) ^ (l15 & 7)) * 8)];

#pragma unroll
        for (int gs = 0; gs < 4; ++gs) {
            int grow = gs * 16 + l15;
            halfx8 bv0 = *(const halfx8*)&vsb[grow * 64 + (((0 + quad) ^ (grow & 7)) * 8)];
            halfx8 bv1 = *(const halfx8*)&vsb[grow * 64 + (((4 + quad) ^ (grow & 7)) * 8)];
            o[gs] = __builtin_amdgcn_mfma_f32_16x16x32_f16(ap0, bv0, o[gs], 0, 0, 0);
            o[gs] = __builtin_amdgcn_mfma_f32_16x16x32_f16(ap1, bv1, o[gs], 0, 0, 0);
        }
    }

    // ---- butterfly 16-lane sum (once), then store ----
    float l[4];
#pragma unroll
    for (int r = 0; r < 4; ++r) {
        float ss = l_lane[r];
#pragma unroll
        for (int off = 1; off < 16; off <<= 1)
            ss += __shfl_xor(ss, off, 64);
        l[r] = ss;
    }
#pragma unroll
    for (int gs = 0; gs < 4; ++gs) {
#pragma unroll
        for (int r = 0; r < 4; ++r) {
            int row = row0 + w * 16 + quad * 4 + r;
            out[row * 64 + gs * 16 + l15] = o[gs][r] / l[r];
        }
    }
}

// ---------------------------------------------------------------------------
extern "C" void kernel_launch(void* const* d_in, const int* in_sizes, int n_in,
                              void* d_out, int out_size, void* d_ws, size_t ws_size,
                              hipStream_t stream) {
    const float* x    = (const float*)d_in[0];
    const int*   vlen = (const int*)  d_in[1];
    const float* Wq   = (const float*)d_in[2];
    const float* bq   = (const float*)d_in[3];
    const float* Wk   = (const float*)d_in[4];
    const float* bk   = (const float*)d_in[5];
    const float* Wv   = (const float*)d_in[6];
    const float* bv   = (const float*)d_in[7];
    float* out = (float*)d_out;

    unsigned short* q_ws  = (unsigned short*)d_ws;
    unsigned short* k_ws  = q_ws + 32768 * 64;
    unsigned short* vt_ws = k_ws + 32768 * 64;

    qkv_proj_kernel<<<512, 256, 0, stream>>>(x, Wq, bq, Wk, bk, Wv, bv, q_ws, k_ws, vt_ws);
    attn_kernel<<<512, 256, 0, stream>>>(q_ws, k_ws, vt_ws, vlen, out);
}